// Round 10
// baseline (151.234 us; speedup 1.0000x reference)
//
#include <hip/hip_runtime.h>
#include <hip/hip_fp16.h>
#include <math.h>

#define DFEAT 128
#define RSH 5            // log2(rows per range) -- 32-row ranges: big gather grid
#define RSZ 32           // rows per range
#define NT  512          // threads per block
#define EPB 4096         // edges per hist/scatter block (196 blocks: fills CUs)
#define EPQ (EPB / NT)   // 8 edges per thread
#define CHUNK 2048       // pairs per sort chunk in gather
#define MAXNR 2048
#define TILESH 10        // scan tile = 1024 elements (2 per thread)
#define TILE (1 << TILESH)
typedef unsigned long long u64;
typedef unsigned int u32;
typedef unsigned short u16;
#define ENDK 0xFFFFFFFFFFFFFFFFULL

__device__ __forceinline__ void elu_store(const float* x, const float* w,
                                          __half* emb2, int i) {
    float4 xv = ((const float4*)x)[i];
    float4 wv = ((const float4*)w)[i & (DFEAT / 4 - 1)];
    float a, r0, r1, r2, r3;
    a = xv.x * wv.x; r0 = 2.0f * (a > 0.0f ? a : (__expf(a) - 1.0f));
    a = xv.y * wv.y; r1 = 2.0f * (a > 0.0f ? a : (__expf(a) - 1.0f));
    a = xv.z * wv.z; r2 = 2.0f * (a > 0.0f ? a : (__expf(a) - 1.0f));
    a = xv.w * wv.w; r3 = 2.0f * (a > 0.0f ? a : (__expf(a) - 1.0f));
    __half2 h01 = __floats2half2_rn(r0, r1);
    __half2 h23 = __floats2half2_rn(r2, r3);
    uint2 pk;
    pk.x = *(u32*)&h01;
    pk.y = *(u32*)&h23;
    ((uint2*)emb2)[i] = pk;
}

// Redundant per-block exclusive scan of tsum[0..nT) into ts[512] (LDS).
__device__ __forceinline__ void scan_tsum_lds(const u32* tsum, u32* ts, int nT) {
    int tid = threadIdx.x;
    u32 v = (tid < nT) ? tsum[tid] : 0u;
    ts[tid] = v;
    __syncthreads();
    for (int d = 1; d < NT; d <<= 1) {
        u32 o = (tid >= d) ? ts[tid - d] : 0u;
        __syncthreads();
        ts[tid] += o;
        __syncthreads();
    }
    u32 incl = ts[tid];
    __syncthreads();
    ts[tid] = incl - v;          // exclusive
    __syncthreads();
}

// K1: blocks [0,EB): LDS histogram of dst>>RSH -> ghist[r][block].
//     blocks [EB,..): elu -> emb2 fp16.
__global__ __launch_bounds__(NT) void hist_elu_kernel(
        const float* __restrict__ x, const float* __restrict__ w,
        __half* __restrict__ emb2, int total4,
        const int* __restrict__ dst, int E,
        u32* __restrict__ ghist, int EB, int NR) {
    if ((int)blockIdx.x < EB) {
        __shared__ u32 hist[MAXNR];
        int tid = threadIdx.x;
        for (int i = tid; i < NR; i += NT) hist[i] = 0;
        __syncthreads();
        int base = blockIdx.x * EPB;
        for (int q = 0; q < EPQ; ++q) {
            int e = base + tid + q * NT;
            if (e < E) atomicAdd(&hist[(((u32)dst[e]) >> RSH) & (MAXNR - 1)], 1u);
        }
        __syncthreads();
        for (int r = tid; r < NR; r += NT)
            ghist[(size_t)r * EB + blockIdx.x] = hist[r];
    } else {
        int idx = (blockIdx.x - EB) * NT + threadIdx.x;
        if (idx < total4) elu_store(x, w, emb2, idx);
    }
}

// K2: per-tile local-exclusive scan, 2 elements per thread (tile = 1024);
// tsum[tile] = tile total.
__global__ __launch_bounds__(NT) void scan_tile_kernel(
        u32* __restrict__ g, u32* __restrict__ tsum, int M) {
    __shared__ u32 sc[NT];
    int tid = threadIdx.x;
    int i0 = (blockIdx.x << TILESH) + 2 * tid;
    int i1 = i0 + 1;
    u32 v0 = (i0 < M) ? g[i0] : 0u;
    u32 v1 = (i1 < M) ? g[i1] : 0u;
    sc[tid] = v0 + v1;
    __syncthreads();
    for (int d = 1; d < NT; d <<= 1) {
        u32 o = (tid >= d) ? sc[tid - d] : 0u;
        __syncthreads();
        sc[tid] += o;
        __syncthreads();
    }
    u32 excl = sc[tid] - (v0 + v1);
    if (i0 < M) g[i0] = excl;
    if (i1 < M) g[i1] = excl + v0;
    if (tid == NT - 1) tsum[blockIdx.x] = sc[NT - 1];
}

// K3: scatter pairs into per-(range,block) contiguous runs; LDS atomics only.
__global__ __launch_bounds__(NT) void scatter_pairs_kernel(
        const int* __restrict__ src, const int* __restrict__ dst, int E,
        const u32* __restrict__ ghist, const u32* __restrict__ tsum,
        int EB, int NR, int nT, u32* __restrict__ pairs) {
    __shared__ u32 ts[NT];
    __shared__ u32 off[MAXNR];
    int tid = threadIdx.x;
    scan_tsum_lds(tsum, ts, nT);
    for (int r = tid; r < NR; r += NT) {
        u32 idx = (u32)r * EB + blockIdx.x;
        off[r] = ghist[idx] + ts[idx >> TILESH];
    }
    __syncthreads();
    int base = blockIdx.x * EPB;
    for (int q = 0; q < EPQ; ++q) {
        int e = base + tid + q * NT;
        if (e < E) {
            u32 d = (u32)dst[e];
            u32 s = (u32)src[e];
            u32 p = atomicAdd(&off[(d >> RSH) & (MAXNR - 1)], 1u);
            if (p < (u32)E) pairs[p] = ((d & (RSZ - 1)) << 16) | s;
        }
    }
}

// K4: one block per 32-row range (NR=1563 blocks -> wave slots saturated).
// LDS counting-sort by local row, then row gather with scalar accumulators
// and 8 clamped loads per batch. s0/s1 clamped (armor).
__global__ __launch_bounds__(NT) void gather_sort_kernel(
        const __half* __restrict__ emb2, const u32* __restrict__ pairs,
        const u32* __restrict__ ghist, const u32* __restrict__ tsum,
        int EB, int NR, int nT, int E,
        float* __restrict__ out, int N) {
    __shared__ u32 ts[NT];
    __shared__ u16 sorted[CHUNK];
    __shared__ u32 bcnt[RSZ + 1];
    __shared__ u32 bstart[RSZ + 1];
    int tid = threadIdx.x;
    scan_tsum_lds(tsum, ts, nT);
    int r = blockIdx.x;
    u32 ia = (u32)r * (u32)EB;
    u32 s0 = ghist[ia] + ts[ia >> TILESH];
    u32 s1 = (r + 1 < NR) ? (ghist[ia + EB] + ts[(ia + EB) >> TILESH]) : (u32)E;
    if (s0 > (u32)E) s0 = (u32)E;
    if (s1 > (u32)E) s1 = (u32)E;
    if (s1 < s0) s1 = s0;
    __syncthreads();
    const int wv = tid >> 6;
    const int lane = tid & 63;
    u32 pos = s0;
    do {
        int csz = 0;
        if (s1 > pos) {
            u32 rem = s1 - pos;
            csz = rem < (u32)CHUNK ? (int)rem : CHUNK;
        }
        if (tid < RSZ + 1) bcnt[tid] = 0;
        __syncthreads();
        u32 p0 = 0, p1 = 0, p2 = 0, p3 = 0;
        int  r0 = -1, r1 = -1, r2 = -1, r3 = -1;
        {
            int e0 = tid, e1 = tid + NT, e2 = tid + 2 * NT, e3 = tid + 3 * NT;
            if (e0 < csz) { p0 = pairs[pos + e0]; r0 = (int)(p0 >> 16); }
            if (e1 < csz) { p1 = pairs[pos + e1]; r1 = (int)(p1 >> 16); }
            if (e2 < csz) { p2 = pairs[pos + e2]; r2 = (int)(p2 >> 16); }
            if (e3 < csz) { p3 = pairs[pos + e3]; r3 = (int)(p3 >> 16); }
            if (r0 >= 0) atomicAdd(&bcnt[r0 & (RSZ - 1)], 1u);
            if (r1 >= 0) atomicAdd(&bcnt[r1 & (RSZ - 1)], 1u);
            if (r2 >= 0) atomicAdd(&bcnt[r2 & (RSZ - 1)], 1u);
            if (r3 >= 0) atomicAdd(&bcnt[r3 & (RSZ - 1)], 1u);
        }
        __syncthreads();
        if (tid < RSZ) {
            u32 vv = bcnt[tid];
            u32 inc = vv;
            for (int d = 1; d < RSZ; d <<= 1) {
                u32 o = __shfl_up(inc, d);
                if (lane >= d) inc += o;
            }
            bstart[tid] = inc - vv;
            bcnt[tid]   = inc - vv;
            if (tid == RSZ - 1) bstart[RSZ] = inc;
        }
        __syncthreads();
        if (r0 >= 0) { u32 p = atomicAdd(&bcnt[r0 & (RSZ - 1)], 1u); sorted[p & (CHUNK - 1)] = (u16)(p0 & 0xFFFFu); }
        if (r1 >= 0) { u32 p = atomicAdd(&bcnt[r1 & (RSZ - 1)], 1u); sorted[p & (CHUNK - 1)] = (u16)(p1 & 0xFFFFu); }
        if (r2 >= 0) { u32 p = atomicAdd(&bcnt[r2 & (RSZ - 1)], 1u); sorted[p & (CHUNK - 1)] = (u16)(p2 & 0xFFFFu); }
        if (r3 >= 0) { u32 p = atomicAdd(&bcnt[r3 & (RSZ - 1)], 1u); sorted[p & (CHUNK - 1)] = (u16)(p3 & 0xFFFFu); }
        __syncthreads();
        // wave wv owns rows [wv*4, wv*4+4)
        for (int rr = 0; rr < 4; ++rr) {
            int row = (wv << 2) + rr;
            int n = (r << RSH) + row;
            int jb = (int)bstart[row], je = (int)bstart[row + 1];
            float ax, ay;
            if (pos != s0 && n < N) {
                float2 t = ((const float2*)out)[(size_t)n * (DFEAT / 2) + lane];
                ax = t.x; ay = t.y;
            } else {
                ax = 0.0f; ay = 0.0f;
            }
            for (int j = jb; j < je; j += 8) {
                int last = je - 1;
                int j1 = j + 1 < last ? j + 1 : last;
                int j2 = j + 2 < last ? j + 2 : last;
                int j3 = j + 3 < last ? j + 3 : last;
                int j4 = j + 4 < last ? j + 4 : last;
                int j5 = j + 5 < last ? j + 5 : last;
                int j6 = j + 6 < last ? j + 6 : last;
                int j7 = j + 7 < last ? j + 7 : last;
                u32 q0 = (u32)sorted[j];
                u32 q1 = (u32)sorted[j1];
                u32 q2 = (u32)sorted[j2];
                u32 q3 = (u32)sorted[j3];
                u32 q4 = (u32)sorted[j4];
                u32 q5 = (u32)sorted[j5];
                u32 q6 = (u32)sorted[j6];
                u32 q7 = (u32)sorted[j7];
                u32 h0 = ((const u32*)(emb2 + (size_t)q0 * DFEAT))[lane];
                u32 h1 = ((const u32*)(emb2 + (size_t)q1 * DFEAT))[lane];
                u32 h2 = ((const u32*)(emb2 + (size_t)q2 * DFEAT))[lane];
                u32 h3 = ((const u32*)(emb2 + (size_t)q3 * DFEAT))[lane];
                u32 h4 = ((const u32*)(emb2 + (size_t)q4 * DFEAT))[lane];
                u32 h5 = ((const u32*)(emb2 + (size_t)q5 * DFEAT))[lane];
                u32 h6 = ((const u32*)(emb2 + (size_t)q6 * DFEAT))[lane];
                u32 h7 = ((const u32*)(emb2 + (size_t)q7 * DFEAT))[lane];
                float2 f0 = __half22float2(*(__half2*)&h0);
                ax += f0.x; ay += f0.y;
                if (j + 1 < je) { float2 f = __half22float2(*(__half2*)&h1); ax += f.x; ay += f.y; }
                if (j + 2 < je) { float2 f = __half22float2(*(__half2*)&h2); ax += f.x; ay += f.y; }
                if (j + 3 < je) { float2 f = __half22float2(*(__half2*)&h3); ax += f.x; ay += f.y; }
                if (j + 4 < je) { float2 f = __half22float2(*(__half2*)&h4); ax += f.x; ay += f.y; }
                if (j + 5 < je) { float2 f = __half22float2(*(__half2*)&h5); ax += f.x; ay += f.y; }
                if (j + 6 < je) { float2 f = __half22float2(*(__half2*)&h6); ax += f.x; ay += f.y; }
                if (j + 7 < je) { float2 f = __half22float2(*(__half2*)&h7); ax += f.x; ay += f.y; }
            }
            if (n < N)
                ((float2*)out)[(size_t)n * (DFEAT / 2) + lane] = make_float2(ax, ay);
        }
        __syncthreads();
        pos += CHUNK;
    } while (pos < s1);
}

// ---------------- fallback paths (unchanged) ----------------

__global__ void bin_elu_ll_kernel(const float* __restrict__ x,
                                  const float* __restrict__ w,
                                  __half* __restrict__ emb2, int total4,
                                  const int* __restrict__ src,
                                  const int* __restrict__ dst, int E,
                                  u64* __restrict__ head,
                                  u64* __restrict__ nxt,
                                  int binBlocks) {
    if ((int)blockIdx.x < binBlocks) {
        int base = blockIdx.x * 1024 + threadIdx.x;
        for (int q = 0; q < 4; ++q) {
            int e = base + q * 256;
            if (e < E) {
                int s = src[e];
                int d = dst[e];
                u64 old = atomicExch(&head[d], ((u64)(u32)s << 32) | (u32)e);
                nxt[e] = old;
            }
        }
    } else {
        int idx = (blockIdx.x - binBlocks) * blockDim.x + threadIdx.x;
        if (idx >= total4) return;
        elu_store(x, w, emb2, idx);
    }
}

__global__ void gather_ll_kernel(const __half* __restrict__ emb2,
                                 const u64* __restrict__ head,
                                 const u64* __restrict__ nxt,
                                 float* __restrict__ out, int N) {
    int wid = (blockIdx.x * blockDim.x + threadIdx.x) >> 6;
    int lane = threadIdx.x & 63;
    int nA = wid * 2;
    int nB = nA + 1;
    if (nA >= N) return;
    bool hasB = (nB < N);
    u64 curA = head[nA];
    u64 curB = hasB ? head[nB] : ENDK;
    float2 accA = make_float2(0.0f, 0.0f);
    float2 accB = make_float2(0.0f, 0.0f);
    while (curA != ENDK || curB != ENDK) {
        bool aA = (curA != ENDK);
        bool aB = (curB != ENDK);
        u64 cA = curA, cB = curB;
        u32 uA = 0, uB = 0;
        if (aA) uA = ((const u32*)(emb2 + ((size_t)(cA >> 32)) * DFEAT))[lane];
        if (aB) uB = ((const u32*)(emb2 + ((size_t)(cB >> 32)) * DFEAT))[lane];
        if (aA) curA = nxt[(u32)cA];
        if (aB) curB = nxt[(u32)cB];
        if (aA) {
            float2 f = __half22float2(*(__half2*)&uA);
            accA.x += f.x; accA.y += f.y;
        }
        if (aB) {
            float2 f = __half22float2(*(__half2*)&uB);
            accB.x += f.x; accB.y += f.y;
        }
    }
    ((float2*)(out + (size_t)nA * DFEAT))[lane] = accA;
    if (hasB) ((float2*)(out + (size_t)nB * DFEAT))[lane] = accB;
}

__global__ void scatter_fused_kernel(const float* __restrict__ x,
                                     const float* __restrict__ w,
                                     const int* __restrict__ src,
                                     const int* __restrict__ dst,
                                     float* __restrict__ out, int E) {
    int t = blockIdx.x * blockDim.x + threadIdx.x;
    int edge = t >> 5;
    int lane = t & 31;
    if (edge >= E) return;
    int s = src[edge];
    int d = dst[edge];
    float4 xv = ((const float4*)(x + (size_t)s * DFEAT))[lane];
    float4 wv = ((const float4*)w)[lane];
    float4 v;
    float a;
    a = xv.x * wv.x; v.x = 2.0f * (a > 0.0f ? a : (__expf(a) - 1.0f));
    a = xv.y * wv.y; v.y = 2.0f * (a > 0.0f ? a : (__expf(a) - 1.0f));
    a = xv.z * wv.z; v.z = 2.0f * (a > 0.0f ? a : (__expf(a) - 1.0f));
    a = xv.w * wv.w; v.w = 2.0f * (a > 0.0f ? a : (__expf(a) - 1.0f));
    float* op = out + (size_t)d * DFEAT + lane * 4;
    unsafeAtomicAdd(op + 0, v.x);
    unsafeAtomicAdd(op + 1, v.y);
    unsafeAtomicAdd(op + 2, v.z);
    unsafeAtomicAdd(op + 3, v.w);
}

extern "C" void kernel_launch(void* const* d_in, const int* in_sizes, int n_in,
                              void* d_out, int out_size, void* d_ws, size_t ws_size,
                              hipStream_t stream) {
    const float* x   = (const float*)d_in[0];   // graph_embedding [N, 128]
    const float* w   = (const float*)d_in[1];   // weight [1, 128]
    const int*   src = (const int*)d_in[3];     // src [E]
    const int*   dst = (const int*)d_in[4];     // dst [E]
    float* out = (float*)d_out;

    const int ND = in_sizes[0];          // N * 128
    const int N  = ND / DFEAT;           // 50000
    const int E  = in_sizes[2];          // 800000

    const int EB = (E + EPB - 1) / EPB;             // hist/scatter blocks (196)
    const int NR = (N + RSZ - 1) >> RSH;            // ranges (1563)
    const int M  = NR * EB;                         // ghist entries (~306K)
    const int nT = (M + TILE - 1) >> TILESH;        // scan tiles (~300)

    size_t emb_bytes   = ((size_t)ND * sizeof(__half) + 15) & ~(size_t)15;   // 12.8 MB
    size_t ghist_bytes = ((size_t)M * sizeof(u32) + 15) & ~(size_t)15;       // ~1.2 MB
    size_t tsum_bytes  = ((size_t)NT * sizeof(u32) + 15) & ~(size_t)15;      // 2 KB
    size_t pairs_bytes = ((size_t)E * sizeof(u32) + 15) & ~(size_t)15;       // 3.2 MB
    size_t total_new = emb_bytes + ghist_bytes + tsum_bytes + pairs_bytes;

    size_t head64_bytes = ((size_t)N * sizeof(u64) + 15) & ~(size_t)15;
    size_t nxt64_bytes  = ((size_t)E * sizeof(u64) + 15) & ~(size_t)15;
    size_t total_old = emb_bytes + head64_bytes + nxt64_bytes;

    int total4 = ND / 4;

    if (ws_size >= total_new && N <= 65536 && NR <= MAXNR && nT <= NT) {
        char* p = (char*)d_ws;
        __half* emb2  = (__half*)p;  p += emb_bytes;
        u32*    ghist = (u32*)p;     p += ghist_bytes;
        u32*    tsum  = (u32*)p;     p += tsum_bytes;
        u32*    pairs = (u32*)p;

        int eluBlocks = (total4 + NT - 1) / NT;
        hist_elu_kernel<<<EB + eluBlocks, NT, 0, stream>>>(
            x, w, emb2, total4, dst, E, ghist, EB, NR);

        scan_tile_kernel<<<nT, NT, 0, stream>>>(ghist, tsum, M);

        scatter_pairs_kernel<<<EB, NT, 0, stream>>>(
            src, dst, E, ghist, tsum, EB, NR, nT, pairs);

        gather_sort_kernel<<<NR, NT, 0, stream>>>(
            emb2, pairs, ghist, tsum, EB, NR, nT, E, out, N);
    } else if (ws_size >= total_old) {
        char* p = (char*)d_ws;
        __half* emb2 = (__half*)p;  p += emb_bytes;
        u64*    head = (u64*)p;     p += head64_bytes;
        u64*    nxt  = (u64*)p;

        hipMemsetAsync(head, 0xFF, (size_t)N * sizeof(u64), stream);

        int eluBlocks256 = (total4 + 255) / 256;
        int binBlocks = (E + 1023) / 1024;
        bin_elu_ll_kernel<<<binBlocks + eluBlocks256, 256, 0, stream>>>(
            x, w, emb2, total4, src, dst, E, head, nxt, binBlocks);

        long long waves = (N + 1) / 2;
        long long thr = waves * 64;
        gather_ll_kernel<<<(int)((thr + 255) / 256), 256, 0, stream>>>(
            emb2, head, nxt, out, N);
    } else {
        hipMemsetAsync(d_out, 0, (size_t)out_size * sizeof(float), stream);
        long long threads = (long long)E * 32;
        scatter_fused_kernel<<<(int)((threads + 255) / 256), 256, 0, stream>>>(x, w, src, dst, out, E);
    }
}

// Round 11
// 137.324 us; speedup vs baseline: 1.1013x; 1.1013x over previous
//
#include <hip/hip_runtime.h>
#include <hip/hip_fp16.h>
#include <math.h>

#define DFEAT 128
#define RSH 5            // log2(rows per gather range)
#define RSZ 32           // rows per gather range
#define SRSH 8           // log2(rows per allocation bucket)
#define MAXB 256         // max buckets (N <= 65536)
#define NT  512          // threads per block
#define EPB 4096         // edges per bin block
#define CAPB 12288       // pair slots per bucket (3x Poisson mean at E=800K,N=50K)
#define GCH 4096         // gather chunk (pairs read per pass)
typedef unsigned long long u64;
typedef unsigned int u32;
typedef unsigned short u16;
#define ENDK 0xFFFFFFFFFFFFFFFFULL

__device__ __forceinline__ void elu_store(const float* x, const float* w,
                                          __half* emb2, int i) {
    float4 xv = ((const float4*)x)[i];
    float4 wv = ((const float4*)w)[i & (DFEAT / 4 - 1)];
    float a, r0, r1, r2, r3;
    a = xv.x * wv.x; r0 = 2.0f * (a > 0.0f ? a : (__expf(a) - 1.0f));
    a = xv.y * wv.y; r1 = 2.0f * (a > 0.0f ? a : (__expf(a) - 1.0f));
    a = xv.z * wv.z; r2 = 2.0f * (a > 0.0f ? a : (__expf(a) - 1.0f));
    a = xv.w * wv.w; r3 = 2.0f * (a > 0.0f ? a : (__expf(a) - 1.0f));
    __half2 h01 = __floats2half2_rn(r0, r1);
    __half2 h23 = __floats2half2_rn(r2, r3);
    uint2 pk;
    pk.x = *(u32*)&h01;
    pk.y = *(u32*)&h23;
    ((uint2*)emb2)[i] = pk;
}

// K1: blocks [0,EB): single-pass binning. LDS per-bucket count (rank = LDS
// atomicAdd return), ONE global atomicAdd per non-empty bucket reserves a
// contiguous run, pairs written at base+rank. Overflow -> tagged spill arena.
// blocks [EB,..): elu -> emb2 fp16.
__global__ __launch_bounds__(NT) void bin_elu_kernel(
        const float* __restrict__ x, const float* __restrict__ w,
        __half* __restrict__ emb2, int total4,
        const int* __restrict__ src, const int* __restrict__ dst, int E,
        u32* __restrict__ gcnt, u32* __restrict__ spillCnt,
        u32* __restrict__ pairs, u32* __restrict__ spill,
        int EB, int NB) {
    if ((int)blockIdx.x < EB) {
        __shared__ u32 lcnt[MAXB];
        __shared__ u32 bbase[MAXB];
        int tid = threadIdx.x;
        for (int i = tid; i < NB; i += NT) lcnt[i] = 0;
        __syncthreads();
        int base = blockIdx.x * EPB;
        // named per-edge state (rule #20: no runtime-indexed arrays)
        u32 m0=~0u,m1=~0u,m2=~0u,m3=~0u,m4=~0u,m5=~0u,m6=~0u,m7=~0u;
        u32 w0=0,w1=0,w2=0,w3=0,w4=0,w5=0,w6=0,w7=0;
#define BIN_LOAD(Q, M, W) { \
        int e = base + tid + Q * NT; \
        if (e < E) { \
            u32 d = (u32)dst[e]; \
            u32 s = (u32)src[e]; \
            u32 b = d >> SRSH; if (b >= (u32)NB) b = (u32)NB - 1u; \
            u32 row = d & ((1u << SRSH) - 1u); \
            u32 rk = atomicAdd(&lcnt[b], 1u); \
            M = (b << 16) | (rk & 0xFFFFu); \
            W = (row << 16) | (s & 0xFFFFu); \
        } }
        BIN_LOAD(0, m0, w0) BIN_LOAD(1, m1, w1) BIN_LOAD(2, m2, w2) BIN_LOAD(3, m3, w3)
        BIN_LOAD(4, m4, w4) BIN_LOAD(5, m5, w5) BIN_LOAD(6, m6, w6) BIN_LOAD(7, m7, w7)
#undef BIN_LOAD
        __syncthreads();
        if (tid < NB) {
            u32 c = lcnt[tid];
            bbase[tid] = c ? atomicAdd(&gcnt[tid], c) : 0u;
        }
        __syncthreads();
#define BIN_WRITE(M, W) if (M != ~0u) { \
        u32 b = M >> 16; u32 rk = M & 0xFFFFu; \
        u32 pos = bbase[b] + rk; \
        if (pos < (u32)CAPB) pairs[(size_t)b * CAPB + pos] = W; \
        else { u32 sp = atomicAdd(spillCnt, 1u); \
               if (sp < (u32)E) spill[sp] = (b << 24) | W; } }
        BIN_WRITE(m0, w0) BIN_WRITE(m1, w1) BIN_WRITE(m2, w2) BIN_WRITE(m3, w3)
        BIN_WRITE(m4, w4) BIN_WRITE(m5, w5) BIN_WRITE(m6, w6) BIN_WRITE(m7, w7)
#undef BIN_WRITE
    } else {
        int idx = (blockIdx.x - EB) * NT + threadIdx.x;
        if (idx < total4) elu_store(x, w, emb2, idx);
    }
}

// K2: one block per 32-row range. bucket = r>>3, sub = r&7. Read the bucket's
// contiguous pair segment (8 sibling blocks share it -> L2 hit), filter by
// sub-range, LDS counting-sort by row (count-rank reused for placement), then
// row gather: scalar accumulators held in registers across chunks, 8 clamped
// independent row loads per batch. Spill scan (normally empty) for armor.
__global__ __launch_bounds__(NT) void gather_bucket_kernel(
        const __half* __restrict__ emb2, const u32* __restrict__ pairs,
        const u32* __restrict__ gcnt, const u32* __restrict__ spillCnt,
        const u32* __restrict__ spill,
        int NR, int E, float* __restrict__ out, int N) {
    __shared__ u16 sorted[GCH];          // 8 KB
    __shared__ u32 bcnt[RSZ + 1];
    __shared__ u32 bstart[RSZ + 1];
    int tid = threadIdx.x;
    int r = blockIdx.x;
    if (r >= NR) return;
    const int wv = tid >> 6;
    const int lane = tid & 63;
    u32 bucket = (u32)(r >> 3);
    u32 sub = (u32)(r & 7);
    u32 cnt = gcnt[bucket];
    u32 seglen = cnt < (u32)CAPB ? cnt : (u32)CAPB;
    size_t segbase = (size_t)bucket * CAPB;
    float ax0 = 0.f, ay0 = 0.f, ax1 = 0.f, ay1 = 0.f;
    float ax2 = 0.f, ay2 = 0.f, ax3 = 0.f, ay3 = 0.f;
    for (u32 cstart = 0; cstart < seglen; cstart += GCH) {
        u32 cend = cstart + GCH < seglen ? cstart + GCH : seglen;
        if (tid < RSZ + 1) bcnt[tid] = 0;
        __syncthreads();
        u32 q0=~0u,q1=~0u,q2=~0u,q3=~0u,q4=~0u,q5=~0u,q6=~0u,q7=~0u;
        u32 s0=0,s1=0,s2=0,s3=0,s4=0,s5=0,s6=0,s7=0;
#define G_CNT(Q, M, V) { \
        u32 i = cstart + (u32)tid + Q * NT; \
        if (i < cend) { \
            u32 pv = pairs[segbase + i]; \
            u32 row = (pv >> 16) & 255u; \
            if ((row >> RSH) == sub) { \
                u32 key = row & (RSZ - 1u); \
                u32 rk = atomicAdd(&bcnt[key], 1u); \
                M = (key << 16) | (rk & 0xFFFFu); V = pv; \
            } } }
        G_CNT(0u, q0, s0) G_CNT(1u, q1, s1) G_CNT(2u, q2, s2) G_CNT(3u, q3, s3)
        G_CNT(4u, q4, s4) G_CNT(5u, q5, s5) G_CNT(6u, q6, s6) G_CNT(7u, q7, s7)
#undef G_CNT
        __syncthreads();
        if (tid < RSZ) {
            u32 vv = bcnt[tid];
            u32 inc = vv;
            for (int d = 1; d < RSZ; d <<= 1) {
                u32 o = __shfl_up(inc, d);
                if (lane >= d) inc += o;
            }
            bstart[tid] = inc - vv;
            if (tid == RSZ - 1) bstart[RSZ] = inc;
        }
        __syncthreads();
#define G_PLACE(M, V) if (M != ~0u) { \
        u32 pos = bstart[M >> 16] + (M & 0xFFFFu); \
        sorted[pos & (GCH - 1u)] = (u16)(V & 0xFFFFu); }
        G_PLACE(q0, s0) G_PLACE(q1, s1) G_PLACE(q2, s2) G_PLACE(q3, s3)
        G_PLACE(q4, s4) G_PLACE(q5, s5) G_PLACE(q6, s6) G_PLACE(q7, s7)
#undef G_PLACE
        __syncthreads();
#define G_ROW(RR, AX, AY) { \
        int row = (wv << 2) + RR; \
        int jb = (int)bstart[row], je = (int)bstart[row + 1]; \
        for (int j = jb; j < je; j += 8) { \
            int last = je - 1; \
            int j1 = j + 1 < last ? j + 1 : last; \
            int j2 = j + 2 < last ? j + 2 : last; \
            int j3 = j + 3 < last ? j + 3 : last; \
            int j4 = j + 4 < last ? j + 4 : last; \
            int j5 = j + 5 < last ? j + 5 : last; \
            int j6 = j + 6 < last ? j + 6 : last; \
            int j7 = j + 7 < last ? j + 7 : last; \
            u32 e0 = (u32)sorted[j];  u32 e1 = (u32)sorted[j1]; \
            u32 e2 = (u32)sorted[j2]; u32 e3 = (u32)sorted[j3]; \
            u32 e4 = (u32)sorted[j4]; u32 e5 = (u32)sorted[j5]; \
            u32 e6 = (u32)sorted[j6]; u32 e7 = (u32)sorted[j7]; \
            u32 h0 = ((const u32*)(emb2 + (size_t)e0 * DFEAT))[lane]; \
            u32 h1 = ((const u32*)(emb2 + (size_t)e1 * DFEAT))[lane]; \
            u32 h2 = ((const u32*)(emb2 + (size_t)e2 * DFEAT))[lane]; \
            u32 h3 = ((const u32*)(emb2 + (size_t)e3 * DFEAT))[lane]; \
            u32 h4 = ((const u32*)(emb2 + (size_t)e4 * DFEAT))[lane]; \
            u32 h5 = ((const u32*)(emb2 + (size_t)e5 * DFEAT))[lane]; \
            u32 h6 = ((const u32*)(emb2 + (size_t)e6 * DFEAT))[lane]; \
            u32 h7 = ((const u32*)(emb2 + (size_t)e7 * DFEAT))[lane]; \
            float2 f0 = __half22float2(*(__half2*)&h0); \
            AX += f0.x; AY += f0.y; \
            if (j + 1 < je) { float2 f = __half22float2(*(__half2*)&h1); AX += f.x; AY += f.y; } \
            if (j + 2 < je) { float2 f = __half22float2(*(__half2*)&h2); AX += f.x; AY += f.y; } \
            if (j + 3 < je) { float2 f = __half22float2(*(__half2*)&h3); AX += f.x; AY += f.y; } \
            if (j + 4 < je) { float2 f = __half22float2(*(__half2*)&h4); AX += f.x; AY += f.y; } \
            if (j + 5 < je) { float2 f = __half22float2(*(__half2*)&h5); AX += f.x; AY += f.y; } \
            if (j + 6 < je) { float2 f = __half22float2(*(__half2*)&h6); AX += f.x; AY += f.y; } \
            if (j + 7 < je) { float2 f = __half22float2(*(__half2*)&h7); AX += f.x; AY += f.y; } \
        } }
        G_ROW(0, ax0, ay0)
        G_ROW(1, ax1, ay1)
        G_ROW(2, ax2, ay2)
        G_ROW(3, ax3, ay3)
#undef G_ROW
        __syncthreads();
    }
    // spill armor (normally spillCnt == 0: one load, no loop)
    u32 spc = *spillCnt;
    if (spc > (u32)E) spc = (u32)E;
    for (u32 i = 0; i < spc; ++i) {
        u32 v = spill[i];
        u32 b = v >> 24;
        u32 row = (v >> 16) & 255u;
        if (b == bucket && (row >> RSH) == sub) {
            u32 rloc = row & (RSZ - 1u);
            if ((int)(rloc >> 2) == wv) {
                u32 h = ((const u32*)(emb2 + (size_t)(v & 0xFFFFu) * DFEAT))[lane];
                float2 f = __half22float2(*(__half2*)&h);
                int rr = (int)(rloc & 3u);
                if (rr == 0) { ax0 += f.x; ay0 += f.y; }
                else if (rr == 1) { ax1 += f.x; ay1 += f.y; }
                else if (rr == 2) { ax2 += f.x; ay2 += f.y; }
                else { ax3 += f.x; ay3 += f.y; }
            }
        }
    }
    int nbase = (r << RSH) + (wv << 2);
    if (nbase + 0 < N) ((float2*)out)[(size_t)(nbase + 0) * (DFEAT / 2) + lane] = make_float2(ax0, ay0);
    if (nbase + 1 < N) ((float2*)out)[(size_t)(nbase + 1) * (DFEAT / 2) + lane] = make_float2(ax1, ay1);
    if (nbase + 2 < N) ((float2*)out)[(size_t)(nbase + 2) * (DFEAT / 2) + lane] = make_float2(ax2, ay2);
    if (nbase + 3 < N) ((float2*)out)[(size_t)(nbase + 3) * (DFEAT / 2) + lane] = make_float2(ax3, ay3);
}

// ---------------- fallback paths (unchanged) ----------------

__global__ void bin_elu_ll_kernel(const float* __restrict__ x,
                                  const float* __restrict__ w,
                                  __half* __restrict__ emb2, int total4,
                                  const int* __restrict__ src,
                                  const int* __restrict__ dst, int E,
                                  u64* __restrict__ head,
                                  u64* __restrict__ nxt,
                                  int binBlocks) {
    if ((int)blockIdx.x < binBlocks) {
        int base = blockIdx.x * 1024 + threadIdx.x;
        for (int q = 0; q < 4; ++q) {
            int e = base + q * 256;
            if (e < E) {
                int s = src[e];
                int d = dst[e];
                u64 old = atomicExch(&head[d], ((u64)(u32)s << 32) | (u32)e);
                nxt[e] = old;
            }
        }
    } else {
        int idx = (blockIdx.x - binBlocks) * blockDim.x + threadIdx.x;
        if (idx >= total4) return;
        elu_store(x, w, emb2, idx);
    }
}

__global__ void gather_ll_kernel(const __half* __restrict__ emb2,
                                 const u64* __restrict__ head,
                                 const u64* __restrict__ nxt,
                                 float* __restrict__ out, int N) {
    int wid = (blockIdx.x * blockDim.x + threadIdx.x) >> 6;
    int lane = threadIdx.x & 63;
    int nA = wid * 2;
    int nB = nA + 1;
    if (nA >= N) return;
    bool hasB = (nB < N);
    u64 curA = head[nA];
    u64 curB = hasB ? head[nB] : ENDK;
    float2 accA = make_float2(0.0f, 0.0f);
    float2 accB = make_float2(0.0f, 0.0f);
    while (curA != ENDK || curB != ENDK) {
        bool aA = (curA != ENDK);
        bool aB = (curB != ENDK);
        u64 cA = curA, cB = curB;
        u32 uA = 0, uB = 0;
        if (aA) uA = ((const u32*)(emb2 + ((size_t)(cA >> 32)) * DFEAT))[lane];
        if (aB) uB = ((const u32*)(emb2 + ((size_t)(cB >> 32)) * DFEAT))[lane];
        if (aA) curA = nxt[(u32)cA];
        if (aB) curB = nxt[(u32)cB];
        if (aA) {
            float2 f = __half22float2(*(__half2*)&uA);
            accA.x += f.x; accA.y += f.y;
        }
        if (aB) {
            float2 f = __half22float2(*(__half2*)&uB);
            accB.x += f.x; accB.y += f.y;
        }
    }
    ((float2*)(out + (size_t)nA * DFEAT))[lane] = accA;
    if (hasB) ((float2*)(out + (size_t)nB * DFEAT))[lane] = accB;
}

__global__ void scatter_fused_kernel(const float* __restrict__ x,
                                     const float* __restrict__ w,
                                     const int* __restrict__ src,
                                     const int* __restrict__ dst,
                                     float* __restrict__ out, int E) {
    int t = blockIdx.x * blockDim.x + threadIdx.x;
    int edge = t >> 5;
    int lane = t & 31;
    if (edge >= E) return;
    int s = src[edge];
    int d = dst[edge];
    float4 xv = ((const float4*)(x + (size_t)s * DFEAT))[lane];
    float4 wv = ((const float4*)w)[lane];
    float4 v;
    float a;
    a = xv.x * wv.x; v.x = 2.0f * (a > 0.0f ? a : (__expf(a) - 1.0f));
    a = xv.y * wv.y; v.y = 2.0f * (a > 0.0f ? a : (__expf(a) - 1.0f));
    a = xv.z * wv.z; v.z = 2.0f * (a > 0.0f ? a : (__expf(a) - 1.0f));
    a = xv.w * wv.w; v.w = 2.0f * (a > 0.0f ? a : (__expf(a) - 1.0f));
    float* op = out + (size_t)d * DFEAT + lane * 4;
    unsafeAtomicAdd(op + 0, v.x);
    unsafeAtomicAdd(op + 1, v.y);
    unsafeAtomicAdd(op + 2, v.z);
    unsafeAtomicAdd(op + 3, v.w);
}

extern "C" void kernel_launch(void* const* d_in, const int* in_sizes, int n_in,
                              void* d_out, int out_size, void* d_ws, size_t ws_size,
                              hipStream_t stream) {
    const float* x   = (const float*)d_in[0];   // graph_embedding [N, 128]
    const float* w   = (const float*)d_in[1];   // weight [1, 128]
    const int*   src = (const int*)d_in[3];     // src [E]
    const int*   dst = (const int*)d_in[4];     // dst [E]
    float* out = (float*)d_out;

    const int ND = in_sizes[0];          // N * 128
    const int N  = ND / DFEAT;           // 50000
    const int E  = in_sizes[2];          // 800000

    const int EB = (E + EPB - 1) / EPB;             // bin blocks (196)
    const int NB = (N + (1 << SRSH) - 1) >> SRSH;   // buckets (196)
    const int NR = (N + RSZ - 1) >> RSH;            // gather ranges (1563)

    size_t emb_bytes   = ((size_t)ND * sizeof(__half) + 15) & ~(size_t)15;        // 12.8 MB
    size_t pairs_bytes = ((size_t)NB * CAPB * sizeof(u32) + 15) & ~(size_t)15;    // ~9.6 MB
    size_t cnt_bytes   = ((size_t)(MAXB + 16) * sizeof(u32) + 15) & ~(size_t)15;  // ~1.1 KB
    size_t spill_bytes = ((size_t)E * sizeof(u32) + 15) & ~(size_t)15;            // 3.2 MB
    size_t total_new = emb_bytes + pairs_bytes + cnt_bytes + spill_bytes;

    size_t head64_bytes = ((size_t)N * sizeof(u64) + 15) & ~(size_t)15;
    size_t nxt64_bytes  = ((size_t)E * sizeof(u64) + 15) & ~(size_t)15;
    size_t total_old = emb_bytes + head64_bytes + nxt64_bytes;

    int total4 = ND / 4;

    if (ws_size >= total_new && N <= 65536 && NB <= MAXB && EPB <= 65536) {
        char* p = (char*)d_ws;
        __half* emb2  = (__half*)p;  p += emb_bytes;
        u32*    pairs = (u32*)p;     p += pairs_bytes;
        u32*    gcnt  = (u32*)p;     p += cnt_bytes;   // [0..MAXB) counters, then spillCnt
        u32*    spill = (u32*)p;
        u32*    spillCnt = gcnt + MAXB;

        // zero bucket counters + spill counter (one tiny memset)
        hipMemsetAsync(gcnt, 0, (size_t)(MAXB + 1) * sizeof(u32), stream);

        int eluBlocks = (total4 + NT - 1) / NT;
        bin_elu_kernel<<<EB + eluBlocks, NT, 0, stream>>>(
            x, w, emb2, total4, src, dst, E,
            gcnt, spillCnt, pairs, spill, EB, NB);

        gather_bucket_kernel<<<NR, NT, 0, stream>>>(
            emb2, pairs, gcnt, spillCnt, spill, NR, E, out, N);
    } else if (ws_size >= total_old) {
        char* p = (char*)d_ws;
        __half* emb2 = (__half*)p;  p += emb_bytes;
        u64*    head = (u64*)p;     p += head64_bytes;
        u64*    nxt  = (u64*)p;

        hipMemsetAsync(head, 0xFF, (size_t)N * sizeof(u64), stream);

        int eluBlocks256 = (total4 + 255) / 256;
        int binBlocks = (E + 1023) / 1024;
        bin_elu_ll_kernel<<<binBlocks + eluBlocks256, 256, 0, stream>>>(
            x, w, emb2, total4, src, dst, E, head, nxt, binBlocks);

        long long waves = (N + 1) / 2;
        long long thr = waves * 64;
        gather_ll_kernel<<<(int)((thr + 255) / 256), 256, 0, stream>>>(
            emb2, head, nxt, out, N);
    } else {
        hipMemsetAsync(d_out, 0, (size_t)out_size * sizeof(float), stream);
        long long threads = (long long)E * 32;
        scatter_fused_kernel<<<(int)((threads + 255) / 256), 256, 0, stream>>>(x, w, src, dst, out, E);
    }
}

// Round 12
// 129.516 us; speedup vs baseline: 1.1677x; 1.0603x over previous
//
#include <hip/hip_runtime.h>
#include <hip/hip_fp16.h>
#include <math.h>

#define DFEAT 128
#define RSH 5            // log2(rows per gather range)
#define RSZ 32           // rows per gather range
#define SRSH 6           // log2(rows per allocation bucket) -- 64-row buckets
#define MAXB 1024        // max buckets (N <= 65536)
#define NT  512          // threads per block
#define EPB 4096         // edges per bin block
#define CAPB 3072        // pair slots per bucket (3x Poisson mean ~1024)
#define GCH 4096         // gather chunk (pairs read per pass)
typedef unsigned long long u64;
typedef unsigned int u32;
typedef unsigned short u16;
#define ENDK 0xFFFFFFFFFFFFFFFFULL

__device__ __forceinline__ void elu_store(const float* x, const float* w,
                                          __half* emb2, int i) {
    float4 xv = ((const float4*)x)[i];
    float4 wv = ((const float4*)w)[i & (DFEAT / 4 - 1)];
    float a, r0, r1, r2, r3;
    a = xv.x * wv.x; r0 = 2.0f * (a > 0.0f ? a : (__expf(a) - 1.0f));
    a = xv.y * wv.y; r1 = 2.0f * (a > 0.0f ? a : (__expf(a) - 1.0f));
    a = xv.z * wv.z; r2 = 2.0f * (a > 0.0f ? a : (__expf(a) - 1.0f));
    a = xv.w * wv.w; r3 = 2.0f * (a > 0.0f ? a : (__expf(a) - 1.0f));
    __half2 h01 = __floats2half2_rn(r0, r1);
    __half2 h23 = __floats2half2_rn(r2, r3);
    uint2 pk;
    pk.x = *(u32*)&h01;
    pk.y = *(u32*)&h23;
    ((uint2*)emb2)[i] = pk;
}

// K1: blocks [0,EB): single-pass binning into 64-row buckets. LDS per-bucket
// count (rank = LDS atomicAdd return), ONE global atomicAdd per non-empty
// bucket reserves a contiguous run, pairs written at base+rank.
// Pair word: (bucket<<22) | (row6<<16) | src16. Overflow -> spill arena.
// blocks [EB,..): elu -> emb2 fp16.
__global__ __launch_bounds__(NT) void bin_elu_kernel(
        const float* __restrict__ x, const float* __restrict__ w,
        __half* __restrict__ emb2, int total4,
        const int* __restrict__ src, const int* __restrict__ dst, int E,
        u32* __restrict__ gcnt, u32* __restrict__ spillCnt,
        u32* __restrict__ pairs, u32* __restrict__ spill,
        int EB, int NB) {
    if ((int)blockIdx.x < EB) {
        __shared__ u32 lcnt[MAXB];
        __shared__ u32 bbase[MAXB];
        int tid = threadIdx.x;
        for (int i = tid; i < NB; i += NT) lcnt[i] = 0;
        __syncthreads();
        int base = blockIdx.x * EPB;
        // named per-edge state (rule #20: no runtime-indexed arrays)
        u32 m0=~0u,m1=~0u,m2=~0u,m3=~0u,m4=~0u,m5=~0u,m6=~0u,m7=~0u;
        u32 w0=0,w1=0,w2=0,w3=0,w4=0,w5=0,w6=0,w7=0;
#define BIN_LOAD(Q, M, W) { \
        int e = base + tid + Q * NT; \
        if (e < E) { \
            u32 d = (u32)dst[e]; \
            u32 s = (u32)src[e]; \
            u32 b = d >> SRSH; if (b >= (u32)NB) b = (u32)NB - 1u; \
            u32 row = d & ((1u << SRSH) - 1u); \
            u32 rk = atomicAdd(&lcnt[b], 1u); \
            M = (b << 16) | (rk & 0xFFFFu); \
            W = (b << 22) | (row << 16) | (s & 0xFFFFu); \
        } }
        BIN_LOAD(0, m0, w0) BIN_LOAD(1, m1, w1) BIN_LOAD(2, m2, w2) BIN_LOAD(3, m3, w3)
        BIN_LOAD(4, m4, w4) BIN_LOAD(5, m5, w5) BIN_LOAD(6, m6, w6) BIN_LOAD(7, m7, w7)
#undef BIN_LOAD
        __syncthreads();
        for (int b = tid; b < NB; b += NT) {
            u32 c = lcnt[b];
            bbase[b] = c ? atomicAdd(&gcnt[b], c) : 0u;
        }
        __syncthreads();
#define BIN_WRITE(M, W) if (M != ~0u) { \
        u32 b = M >> 16; u32 rk = M & 0xFFFFu; \
        u32 pos = bbase[b] + rk; \
        if (pos < (u32)CAPB) pairs[(size_t)b * CAPB + pos] = W; \
        else { u32 sp = atomicAdd(spillCnt, 1u); \
               if (sp < (u32)E) spill[sp] = W; } }
        BIN_WRITE(m0, w0) BIN_WRITE(m1, w1) BIN_WRITE(m2, w2) BIN_WRITE(m3, w3)
        BIN_WRITE(m4, w4) BIN_WRITE(m5, w5) BIN_WRITE(m6, w6) BIN_WRITE(m7, w7)
#undef BIN_WRITE
    } else {
        int idx = (blockIdx.x - EB) * NT + threadIdx.x;
        if (idx < total4) elu_store(x, w, emb2, idx);
    }
}

// K2: one block per 32-row range. bucket = r>>1, sub = r&1. Read the bucket's
// contiguous pair segment (2 sibling blocks share it -> L2 hit), filter by
// sub-range, LDS counting-sort by row (count-rank reused for placement), then
// row gather: scalar accumulators in registers across chunks, 8 clamped
// independent row loads per batch. Spill scan (normally empty) for armor.
__global__ __launch_bounds__(NT) void gather_bucket_kernel(
        const __half* __restrict__ emb2, const u32* __restrict__ pairs,
        const u32* __restrict__ gcnt, const u32* __restrict__ spillCnt,
        const u32* __restrict__ spill,
        int NR, int E, float* __restrict__ out, int N) {
    __shared__ u16 sorted[GCH];          // 8 KB
    __shared__ u32 bcnt[RSZ + 1];
    __shared__ u32 bstart[RSZ + 1];
    int tid = threadIdx.x;
    int r = blockIdx.x;
    if (r >= NR) return;
    const int wv = tid >> 6;
    const int lane = tid & 63;
    u32 bucket = (u32)(r >> 1);
    u32 sub = (u32)(r & 1);
    u32 cnt = gcnt[bucket];
    u32 seglen = cnt < (u32)CAPB ? cnt : (u32)CAPB;
    size_t segbase = (size_t)bucket * CAPB;
    float ax0 = 0.f, ay0 = 0.f, ax1 = 0.f, ay1 = 0.f;
    float ax2 = 0.f, ay2 = 0.f, ax3 = 0.f, ay3 = 0.f;
    for (u32 cstart = 0; cstart < seglen; cstart += GCH) {
        u32 cend = cstart + GCH < seglen ? cstart + GCH : seglen;
        if (tid < RSZ + 1) bcnt[tid] = 0;
        __syncthreads();
        u32 q0=~0u,q1=~0u,q2=~0u,q3=~0u,q4=~0u,q5=~0u,q6=~0u,q7=~0u;
        u32 s0=0,s1=0,s2=0,s3=0,s4=0,s5=0,s6=0,s7=0;
#define G_CNT(Q, M, V) { \
        u32 i = cstart + (u32)tid + Q * NT; \
        if (i < cend) { \
            u32 pv = pairs[segbase + i]; \
            u32 row = (pv >> 16) & 63u; \
            if ((row >> RSH) == sub) { \
                u32 key = row & (RSZ - 1u); \
                u32 rk = atomicAdd(&bcnt[key], 1u); \
                M = (key << 16) | (rk & 0xFFFFu); V = pv; \
            } } }
        G_CNT(0u, q0, s0) G_CNT(1u, q1, s1) G_CNT(2u, q2, s2) G_CNT(3u, q3, s3)
        G_CNT(4u, q4, s4) G_CNT(5u, q5, s5) G_CNT(6u, q6, s6) G_CNT(7u, q7, s7)
#undef G_CNT
        __syncthreads();
        if (tid < RSZ) {
            u32 vv = bcnt[tid];
            u32 inc = vv;
            for (int d = 1; d < RSZ; d <<= 1) {
                u32 o = __shfl_up(inc, d);
                if (lane >= d) inc += o;
            }
            bstart[tid] = inc - vv;
            if (tid == RSZ - 1) bstart[RSZ] = inc;
        }
        __syncthreads();
#define G_PLACE(M, V) if (M != ~0u) { \
        u32 pos = bstart[M >> 16] + (M & 0xFFFFu); \
        sorted[pos & (GCH - 1u)] = (u16)(V & 0xFFFFu); }
        G_PLACE(q0, s0) G_PLACE(q1, s1) G_PLACE(q2, s2) G_PLACE(q3, s3)
        G_PLACE(q4, s4) G_PLACE(q5, s5) G_PLACE(q6, s6) G_PLACE(q7, s7)
#undef G_PLACE
        __syncthreads();
#define G_ROW(RR, AX, AY) { \
        int row = (wv << 2) + RR; \
        int jb = (int)bstart[row], je = (int)bstart[row + 1]; \
        for (int j = jb; j < je; j += 8) { \
            int last = je - 1; \
            int j1 = j + 1 < last ? j + 1 : last; \
            int j2 = j + 2 < last ? j + 2 : last; \
            int j3 = j + 3 < last ? j + 3 : last; \
            int j4 = j + 4 < last ? j + 4 : last; \
            int j5 = j + 5 < last ? j + 5 : last; \
            int j6 = j + 6 < last ? j + 6 : last; \
            int j7 = j + 7 < last ? j + 7 : last; \
            u32 e0 = (u32)sorted[j];  u32 e1 = (u32)sorted[j1]; \
            u32 e2 = (u32)sorted[j2]; u32 e3 = (u32)sorted[j3]; \
            u32 e4 = (u32)sorted[j4]; u32 e5 = (u32)sorted[j5]; \
            u32 e6 = (u32)sorted[j6]; u32 e7 = (u32)sorted[j7]; \
            u32 h0 = ((const u32*)(emb2 + (size_t)e0 * DFEAT))[lane]; \
            u32 h1 = ((const u32*)(emb2 + (size_t)e1 * DFEAT))[lane]; \
            u32 h2 = ((const u32*)(emb2 + (size_t)e2 * DFEAT))[lane]; \
            u32 h3 = ((const u32*)(emb2 + (size_t)e3 * DFEAT))[lane]; \
            u32 h4 = ((const u32*)(emb2 + (size_t)e4 * DFEAT))[lane]; \
            u32 h5 = ((const u32*)(emb2 + (size_t)e5 * DFEAT))[lane]; \
            u32 h6 = ((const u32*)(emb2 + (size_t)e6 * DFEAT))[lane]; \
            u32 h7 = ((const u32*)(emb2 + (size_t)e7 * DFEAT))[lane]; \
            float2 f0 = __half22float2(*(__half2*)&h0); \
            AX += f0.x; AY += f0.y; \
            if (j + 1 < je) { float2 f = __half22float2(*(__half2*)&h1); AX += f.x; AY += f.y; } \
            if (j + 2 < je) { float2 f = __half22float2(*(__half2*)&h2); AX += f.x; AY += f.y; } \
            if (j + 3 < je) { float2 f = __half22float2(*(__half2*)&h3); AX += f.x; AY += f.y; } \
            if (j + 4 < je) { float2 f = __half22float2(*(__half2*)&h4); AX += f.x; AY += f.y; } \
            if (j + 5 < je) { float2 f = __half22float2(*(__half2*)&h5); AX += f.x; AY += f.y; } \
            if (j + 6 < je) { float2 f = __half22float2(*(__half2*)&h6); AX += f.x; AY += f.y; } \
            if (j + 7 < je) { float2 f = __half22float2(*(__half2*)&h7); AX += f.x; AY += f.y; } \
        } }
        G_ROW(0, ax0, ay0)
        G_ROW(1, ax1, ay1)
        G_ROW(2, ax2, ay2)
        G_ROW(3, ax3, ay3)
#undef G_ROW
        __syncthreads();
    }
    // spill armor (normally spillCnt == 0: one load, no loop)
    u32 spc = *spillCnt;
    if (spc > (u32)E) spc = (u32)E;
    for (u32 i = 0; i < spc; ++i) {
        u32 v = spill[i];
        u32 b = v >> 22;
        u32 row = (v >> 16) & 63u;
        if (b == bucket && (row >> RSH) == sub) {
            u32 rloc = row & (RSZ - 1u);
            if ((int)(rloc >> 2) == wv) {
                u32 h = ((const u32*)(emb2 + (size_t)(v & 0xFFFFu) * DFEAT))[lane];
                float2 f = __half22float2(*(__half2*)&h);
                int rr = (int)(rloc & 3u);
                if (rr == 0) { ax0 += f.x; ay0 += f.y; }
                else if (rr == 1) { ax1 += f.x; ay1 += f.y; }
                else if (rr == 2) { ax2 += f.x; ay2 += f.y; }
                else { ax3 += f.x; ay3 += f.y; }
            }
        }
    }
    int nbase = (r << RSH) + (wv << 2);
    if (nbase + 0 < N) ((float2*)out)[(size_t)(nbase + 0) * (DFEAT / 2) + lane] = make_float2(ax0, ay0);
    if (nbase + 1 < N) ((float2*)out)[(size_t)(nbase + 1) * (DFEAT / 2) + lane] = make_float2(ax1, ay1);
    if (nbase + 2 < N) ((float2*)out)[(size_t)(nbase + 2) * (DFEAT / 2) + lane] = make_float2(ax2, ay2);
    if (nbase + 3 < N) ((float2*)out)[(size_t)(nbase + 3) * (DFEAT / 2) + lane] = make_float2(ax3, ay3);
}

// ---------------- fallback paths (unchanged) ----------------

__global__ void bin_elu_ll_kernel(const float* __restrict__ x,
                                  const float* __restrict__ w,
                                  __half* __restrict__ emb2, int total4,
                                  const int* __restrict__ src,
                                  const int* __restrict__ dst, int E,
                                  u64* __restrict__ head,
                                  u64* __restrict__ nxt,
                                  int binBlocks) {
    if ((int)blockIdx.x < binBlocks) {
        int base = blockIdx.x * 1024 + threadIdx.x;
        for (int q = 0; q < 4; ++q) {
            int e = base + q * 256;
            if (e < E) {
                int s = src[e];
                int d = dst[e];
                u64 old = atomicExch(&head[d], ((u64)(u32)s << 32) | (u32)e);
                nxt[e] = old;
            }
        }
    } else {
        int idx = (blockIdx.x - binBlocks) * blockDim.x + threadIdx.x;
        if (idx >= total4) return;
        elu_store(x, w, emb2, idx);
    }
}

__global__ void gather_ll_kernel(const __half* __restrict__ emb2,
                                 const u64* __restrict__ head,
                                 const u64* __restrict__ nxt,
                                 float* __restrict__ out, int N) {
    int wid = (blockIdx.x * blockDim.x + threadIdx.x) >> 6;
    int lane = threadIdx.x & 63;
    int nA = wid * 2;
    int nB = nA + 1;
    if (nA >= N) return;
    bool hasB = (nB < N);
    u64 curA = head[nA];
    u64 curB = hasB ? head[nB] : ENDK;
    float2 accA = make_float2(0.0f, 0.0f);
    float2 accB = make_float2(0.0f, 0.0f);
    while (curA != ENDK || curB != ENDK) {
        bool aA = (curA != ENDK);
        bool aB = (curB != ENDK);
        u64 cA = curA, cB = curB;
        u32 uA = 0, uB = 0;
        if (aA) uA = ((const u32*)(emb2 + ((size_t)(cA >> 32)) * DFEAT))[lane];
        if (aB) uB = ((const u32*)(emb2 + ((size_t)(cB >> 32)) * DFEAT))[lane];
        if (aA) curA = nxt[(u32)cA];
        if (aB) curB = nxt[(u32)cB];
        if (aA) {
            float2 f = __half22float2(*(__half2*)&uA);
            accA.x += f.x; accA.y += f.y;
        }
        if (aB) {
            float2 f = __half22float2(*(__half2*)&uB);
            accB.x += f.x; accB.y += f.y;
        }
    }
    ((float2*)(out + (size_t)nA * DFEAT))[lane] = accA;
    if (hasB) ((float2*)(out + (size_t)nB * DFEAT))[lane] = accB;
}

__global__ void scatter_fused_kernel(const float* __restrict__ x,
                                     const float* __restrict__ w,
                                     const int* __restrict__ src,
                                     const int* __restrict__ dst,
                                     float* __restrict__ out, int E) {
    int t = blockIdx.x * blockDim.x + threadIdx.x;
    int edge = t >> 5;
    int lane = t & 31;
    if (edge >= E) return;
    int s = src[edge];
    int d = dst[edge];
    float4 xv = ((const float4*)(x + (size_t)s * DFEAT))[lane];
    float4 wv = ((const float4*)w)[lane];
    float4 v;
    float a;
    a = xv.x * wv.x; v.x = 2.0f * (a > 0.0f ? a : (__expf(a) - 1.0f));
    a = xv.y * wv.y; v.y = 2.0f * (a > 0.0f ? a : (__expf(a) - 1.0f));
    a = xv.z * wv.z; v.z = 2.0f * (a > 0.0f ? a : (__expf(a) - 1.0f));
    a = xv.w * wv.w; v.w = 2.0f * (a > 0.0f ? a : (__expf(a) - 1.0f));
    float* op = out + (size_t)d * DFEAT + lane * 4;
    unsafeAtomicAdd(op + 0, v.x);
    unsafeAtomicAdd(op + 1, v.y);
    unsafeAtomicAdd(op + 2, v.z);
    unsafeAtomicAdd(op + 3, v.w);
}

extern "C" void kernel_launch(void* const* d_in, const int* in_sizes, int n_in,
                              void* d_out, int out_size, void* d_ws, size_t ws_size,
                              hipStream_t stream) {
    const float* x   = (const float*)d_in[0];   // graph_embedding [N, 128]
    const float* w   = (const float*)d_in[1];   // weight [1, 128]
    const int*   src = (const int*)d_in[3];     // src [E]
    const int*   dst = (const int*)d_in[4];     // dst [E]
    float* out = (float*)d_out;

    const int ND = in_sizes[0];          // N * 128
    const int N  = ND / DFEAT;           // 50000
    const int E  = in_sizes[2];          // 800000

    const int EB = (E + EPB - 1) / EPB;             // bin blocks (196)
    const int NB = (N + (1 << SRSH) - 1) >> SRSH;   // buckets (782)
    const int NR = (N + RSZ - 1) >> RSH;            // gather ranges (1563)

    size_t emb_bytes   = ((size_t)ND * sizeof(__half) + 15) & ~(size_t)15;        // 12.8 MB
    size_t pairs_bytes = ((size_t)NB * CAPB * sizeof(u32) + 15) & ~(size_t)15;    // ~9.6 MB
    size_t cnt_bytes   = ((size_t)(MAXB + 16) * sizeof(u32) + 15) & ~(size_t)15;  // ~4.2 KB
    size_t spill_bytes = ((size_t)E * sizeof(u32) + 15) & ~(size_t)15;            // 3.2 MB
    size_t total_new = emb_bytes + pairs_bytes + cnt_bytes + spill_bytes;

    size_t head64_bytes = ((size_t)N * sizeof(u64) + 15) & ~(size_t)15;
    size_t nxt64_bytes  = ((size_t)E * sizeof(u64) + 15) & ~(size_t)15;
    size_t total_old = emb_bytes + head64_bytes + nxt64_bytes;

    int total4 = ND / 4;

    if (ws_size >= total_new && N <= 65536 && NB <= MAXB) {
        char* p = (char*)d_ws;
        __half* emb2  = (__half*)p;  p += emb_bytes;
        u32*    pairs = (u32*)p;     p += pairs_bytes;
        u32*    gcnt  = (u32*)p;     p += cnt_bytes;   // [0..MAXB) counters, then spillCnt
        u32*    spill = (u32*)p;
        u32*    spillCnt = gcnt + MAXB;

        // zero bucket counters + spill counter (one tiny memset)
        hipMemsetAsync(gcnt, 0, (size_t)(MAXB + 1) * sizeof(u32), stream);

        int eluBlocks = (total4 + NT - 1) / NT;
        bin_elu_kernel<<<EB + eluBlocks, NT, 0, stream>>>(
            x, w, emb2, total4, src, dst, E,
            gcnt, spillCnt, pairs, spill, EB, NB);

        gather_bucket_kernel<<<NR, NT, 0, stream>>>(
            emb2, pairs, gcnt, spillCnt, spill, NR, E, out, N);
    } else if (ws_size >= total_old) {
        char* p = (char*)d_ws;
        __half* emb2 = (__half*)p;  p += emb_bytes;
        u64*    head = (u64*)p;     p += head64_bytes;
        u64*    nxt  = (u64*)p;

        hipMemsetAsync(head, 0xFF, (size_t)N * sizeof(u64), stream);

        int eluBlocks256 = (total4 + 255) / 256;
        int binBlocks = (E + 1023) / 1024;
        bin_elu_ll_kernel<<<binBlocks + eluBlocks256, 256, 0, stream>>>(
            x, w, emb2, total4, src, dst, E, head, nxt, binBlocks);

        long long waves = (N + 1) / 2;
        long long thr = waves * 64;
        gather_ll_kernel<<<(int)((thr + 255) / 256), 256, 0, stream>>>(
            emb2, head, nxt, out, N);
    } else {
        hipMemsetAsync(d_out, 0, (size_t)out_size * sizeof(float), stream);
        long long threads = (long long)E * 32;
        scatter_fused_kernel<<<(int)((threads + 255) / 256), 256, 0, stream>>>(x, w, src, dst, out, E);
    }
}